// Round 8
// baseline (441.605 us; speedup 1.0000x reference)
//
#include <hip/hip_runtime.h>

// Species-routed expert Linear as a bucketed grouped GEMM.
//   out[a] = rho[a] @ W[sym[a]] + b[sym[a]]   (NTA=65536, K=N=512, 4 species)
// R8: ADDRESS-RANGE-LOCAL grouping. Block (g,s) handles the species-s atoms
//     of range [g*256,(g+1)*256). The 4 sibling blocks of a range cover its
//     512KB rho/out window exactly once (union = linear sweep); XCD-swizzle
//     co-locates siblings on one XCD for L2/DRAM-page locality. Rows/block
//     ~64+-7 (cap 128, 9-sigma). K-tiled double-buffered LDS, merged 64B
//     staging sectors, 0-conflict LDS layout (measured), dynamic mf count.

#define NTA   65536
#define DIM_O 512
#define NMAXD 512
#define NSPE  4
#define RNG   256
#define NRNG  (NTA / RNG)
#define CAP   128
#define BK    64

typedef __attribute__((ext_vector_type(4))) float  f32x4;
typedef __attribute__((ext_vector_type(8))) short  bf16x8;
typedef __attribute__((ext_vector_type(4))) short  bf16x4;

__device__ __forceinline__ short f2bf(float f) {
    unsigned u = __builtin_bit_cast(unsigned, f);
    u += 0x7FFFu + ((u >> 16) & 1u);
    return (short)(u >> 16);
}

// Per-range species compaction: no atomics, order-stable within range.
__global__ void range_lists_kernel(const int* __restrict__ sym,
                                   int* __restrict__ rcnt,
                                   int* __restrict__ rl) {
    const int g = blockIdx.x, tid = threadIdx.x;
    const int w = tid >> 6, lane = tid & 63;
    const int a = g * RNG + tid;
    const int s = sym[a];
    __shared__ int wcnt[4][NSPE];
    unsigned long long m0, m1, m2, m3;
    m0 = __ballot(s == 0); if (lane == 0) wcnt[w][0] = __popcll(m0);
    m1 = __ballot(s == 1); if (lane == 0) wcnt[w][1] = __popcll(m1);
    m2 = __ballot(s == 2); if (lane == 0) wcnt[w][2] = __popcll(m2);
    m3 = __ballot(s == 3); if (lane == 0) wcnt[w][3] = __popcll(m3);
    __syncthreads();
    int base = 0;
    #pragma unroll
    for (int spe = 0; spe < NSPE; ++spe)
        #pragma unroll
        for (int ww = 0; ww < 4; ++ww)
            if ((spe < s) || (spe == s && ww < w)) base += wcnt[ww][spe];
    unsigned long long mm = (s == 0) ? m0 : (s == 1) ? m1 : (s == 2) ? m2 : m3;
    const int pos = __popcll(mm & ((1ull << lane) - 1ull));
    rl[g * RNG + base + pos] = a;
    if (tid < NSPE)
        rcnt[g * NSPE + tid] = wcnt[0][tid] + wcnt[1][tid] + wcnt[2][tid] + wcnt[3][tid];
}

// Pack W[s][k][n] (fp32) -> bf16 MFMA-B fragment layout (unchanged, proven).
__global__ void pack_w_kernel(const float* __restrict__ W, short* __restrict__ Wp) {
    int idx = blockIdx.x * 256 + threadIdx.x;
    int j  = idx & 7;
    int l  = (idx >> 3) & 63;
    int nb = (idx >> 9) & 31;
    int kb = (idx >> 14) & 15;
    int s  = idx >> 18;
    int k = kb * 32 + (l >> 4) * 8 + j;
    int n = nb * 16 + (l & 15);
    Wp[idx] = f2bf(W[((size_t)s * DIM_O + k) * NMAXD + n]);
}

// LDS A: 16B slot = c*CAP + row (c = k-chunk of 8 floats, 0..7), half h in slot.
// Write banks 2-way, read (b128, 16 rows/lane-group) 2-way: both free (m136).
__global__ __launch_bounds__(512, 4)
void gemm_kernel(const float* __restrict__ rho,
                 const short* __restrict__ Wp,
                 const float* __restrict__ bias,
                 const int*  __restrict__ rcnt,
                 const int*  __restrict__ rl,
                 float* __restrict__ out)
{
    // XCD-swizzle: siblings (g, s=0..3) share an XCD in consecutive slots.
    const int b    = blockIdx.x;
    const int xcd  = b & 7;
    const int slot = b >> 3;
    const int s    = slot & 3;
    const int g    = (slot >> 2) * 8 + xcd;

    const int4 rc = *(const int4*)&rcnt[g * 4];
    const int cnt = (s == 0) ? rc.x : (s == 1) ? rc.y : (s == 2) ? rc.z : rc.w;
    int base = 0;
    if (s > 0) base += rc.x;
    if (s > 1) base += rc.y;
    if (s > 2) base += rc.z;
    if (cnt == 0) return;

    __shared__ int aidx[CAP];
    __shared__ __align__(16) short Abuf[2][8 * CAP * 8];   // 2 x 16 KB

    const int tid  = threadIdx.x;
    const int lane = tid & 63;
    const int w    = tid >> 6;           // wave 0..7 owns cols [w*64, w*64+64)
    const int lrow = lane & 15;
    const int lgr  = lane >> 4;

    if (tid < CAP)
        aidx[tid] = rl[g * RNG + base + min(tid, cnt - 1)];
    __syncthreads();

    // staging: 4 threads/row; load #i = 16B at row-byte (i*64 + p*16):
    // 4-lane group covers a full 64B sector per instruction (merges).
    const int  srow = tid >> 2;          // 0..127
    const int  p    = tid & 3;
    const bool sv   = srow < cnt;
    const float* gsrc = rho + (size_t)aidx[srow] * DIM_O + p * 4;
    const int h    = p & 1;
    const int c_lo = p >> 1;

    const short* wbase = Wp + ((size_t)s * 512 + w * 4) * 512 + lane * 8;

    const int nmf = (cnt + 15) >> 4;     // active 16-row fragments (1..8)

    f32x4 acc[8][4];
    #pragma unroll
    for (int m = 0; m < 8; ++m)
        #pragma unroll
        for (int n = 0; n < 4; ++n) acc[m][n] = (f32x4)0.0f;

    f32x4 st[4];
    #define ISSUE(kt)                                                       \
        if (sv) {                                                           \
            _Pragma("unroll")                                               \
            for (int i = 0; i < 4; ++i)                                     \
                st[i] = *(const f32x4*)(gsrc + (kt) * BK + i * 16);         \
        }
    #define WRITEA(bb)                                                      \
        if (sv) {                                                           \
            _Pragma("unroll")                                               \
            for (int i = 0; i < 4; ++i) {                                   \
                bf16x4 t4;                                                  \
                _Pragma("unroll")                                           \
                for (int q = 0; q < 4; ++q) t4[q] = f2bf(st[i][q]);         \
                *(bf16x4*)&Abuf[bb][((2 * i + c_lo) * CAP + srow) * 8 + h * 4] = t4; \
            }                                                               \
        }

    ISSUE(0);
    WRITEA(0);
    __syncthreads();

    for (int kt = 0; kt < 8; ++kt) {
        const int buf = kt & 1;
        if (kt < 7) ISSUE(kt + 1);
        #pragma unroll
        for (int ks = 0; ks < 2; ++ks) {
            bf16x8 bfrag[4];
            #pragma unroll
            for (int nf = 0; nf < 4; ++nf)
                bfrag[nf] = *(const bf16x8*)
                    (wbase + (size_t)((kt * 2 + ks) * 32 + nf) * 512);
            #pragma unroll
            for (int mf = 0; mf < 8; ++mf) {
                if (mf < nmf) {   // block-uniform
                    const int c = ks * 4 + lgr;
                    const bf16x8 afrag =
                        *(const bf16x8*)&Abuf[buf][(c * CAP + mf * 16 + lrow) * 8];
                    #pragma unroll
                    for (int nf = 0; nf < 4; ++nf)
                        acc[mf][nf] = __builtin_amdgcn_mfma_f32_16x16x32_bf16(
                            afrag, bfrag[nf], acc[mf][nf], 0, 0, 0);
                }
            }
        }
        if (kt < 7) {
            WRITEA(buf ^ 1);
            __syncthreads();
        }
    }
    #undef ISSUE
    #undef WRITEA

    // epilogue: bias + per-row store (16 lanes x 64B contiguous per row);
    // rows of all 4 siblings tile the range's out-window densely.
    float bv[4];
    #pragma unroll
    for (int nf = 0; nf < 4; ++nf)
        bv[nf] = bias[s * NMAXD + w * 64 + nf * 16 + lrow];
    #pragma unroll
    for (int mf = 0; mf < 8; ++mf) {
        if (mf < nmf) {
            #pragma unroll
            for (int q = 0; q < 4; ++q) {
                const int r = mf * 16 + lgr * 4 + q;
                if (r < cnt) {
                    float* orow = out + (size_t)aidx[r] * NMAXD + w * 64 + lrow;
                    #pragma unroll
                    for (int nf = 0; nf < 4; ++nf)
                        orow[nf * 16] = acc[mf][nf][q] + bv[nf];
                }
            }
        }
    }
}

extern "C" void kernel_launch(void* const* d_in, const int* in_sizes, int n_in,
                              void* d_out, int out_size, void* d_ws, size_t ws_size,
                              hipStream_t stream) {
    const float* rho = (const float*)d_in[0];
    const float* W   = (const float*)d_in[1];
    const float* b   = (const float*)d_in[2];
    const int*   sym = (const int*)d_in[3];
    float* out = (float*)d_out;

    int*   rcnt = (int*)d_ws;                                   // 4 KB
    int*   rl   = (int*)((char*)d_ws + 4096);                   // 256 KB
    short* Wp   = (short*)((char*)d_ws + 4096 + NTA * 4);       // 2 MB

    pack_w_kernel<<<(NSPE * DIM_O * NMAXD) / 256, 256, 0, stream>>>(W, Wp);
    range_lists_kernel<<<NRNG, 256, 0, stream>>>(sym, rcnt, rl);
    gemm_kernel<<<NRNG * NSPE, 512, 0, stream>>>(rho, Wp, b, rcnt, rl, out);
}

// Round 9
// 201.814 us; speedup vs baseline: 2.1882x; 2.1882x over previous
//
#include <hip/hip_runtime.h>

// R9 = DECISIVE MEASUREMENT ROUND (kernel still passes: real gemm runs last).
// Dispatches: pack_w, build_lists, stream<1> (scatter row-copy via species
// lists), stream<0> (linear row-copy), gemm<0> (R6 minus stores, keepalive),
// gemm<1> (real R6, correct output). Each gets its own rocprof row.

#define NTA   65536
#define DIM_O 512
#define NMAXD 512
#define NSPE  4
#define BM    64
#define BK    64

typedef __attribute__((ext_vector_type(4))) float  f32x4;
typedef __attribute__((ext_vector_type(8))) short  bf16x8;
typedef __attribute__((ext_vector_type(4))) short  bf16x4;

__device__ __forceinline__ short f2bf(float f) {
    unsigned u = __builtin_bit_cast(unsigned, f);
    u += 0x7FFFu + ((u >> 16) & 1u);
    return (short)(u >> 16);
}

__global__ void build_lists_kernel(const int* __restrict__ sym,
                                   int* __restrict__ counts,
                                   int* __restrict__ lists) {
    int i = blockIdx.x * 256 + threadIdx.x;
    int s = sym[i];
    int lane = threadIdx.x & 63;
    #pragma unroll
    for (int spe = 0; spe < NSPE; ++spe) {
        unsigned long long m = __ballot(s == spe);
        if (m == 0ull) continue;
        int leader = __ffsll(m) - 1;
        int base = 0;
        if (lane == leader) base = atomicAdd(&counts[spe], __popcll(m));
        base = __shfl(base, leader);
        if (s == spe) {
            int pos = __popcll(m & ((1ull << lane) - 1ull));
            lists[spe * NTA + base + pos] = i;
        }
    }
}

__global__ void pack_w_kernel(const float* __restrict__ W, short* __restrict__ Wp,
                              int* __restrict__ counts) {
    if (blockIdx.x == 0 && threadIdx.x < NSPE) counts[threadIdx.x] = 0;
    int idx = blockIdx.x * 256 + threadIdx.x;
    int j  = idx & 7;
    int l  = (idx >> 3) & 63;
    int nb = (idx >> 9) & 31;
    int kb = (idx >> 14) & 15;
    int s  = idx >> 18;
    int k = kb * 32 + (l >> 4) * 8 + j;
    int n = nb * 16 + (l & 15);
    Wp[idx] = f2bf(W[((size_t)s * DIM_O + k) * NMAXD + n]);
}

// Pure row-copy stream probe. 4096 blocks x 256 threads; 16 threads/row,
// each thread moves 2 x f32x4 (128 B). SCATTER=1: rows via species lists
// (same statistics as gemm's gather/scatter). SCATTER=0: linear rows.
template<int SCATTER>
__global__ __launch_bounds__(256)
void stream_tpl(const float* __restrict__ rho, float* __restrict__ out,
                const int* __restrict__ counts, const int* __restrict__ lists) {
    const int ri = blockIdx.x * 16 + (threadIdx.x >> 4);
    int row;
    if constexpr (SCATTER) {
        const int s = ri >> 14;
        const int i = ri & 16383;
        const int c = counts[s];
        row = lists[s * NTA + min(i, c - 1)];
    } else {
        row = ri;
    }
    const f32x4* src = (const f32x4*)(rho + (size_t)row * DIM_O) + (threadIdx.x & 15) * 2;
    f32x4*       dst = (f32x4*)(out + (size_t)row * DIM_O) + (threadIdx.x & 15) * 2;
    f32x4 a = src[0], b = src[1];
    dst[0] = a; dst[1] = b;
}

// R6 gemm: full A-tile prologue gather -> 64KB LDS, barrier-free K-loop.
// STORE=0: keepalive instead of global stores.
template<int STORE>
__global__ __launch_bounds__(512, 4)
void gemm_tpl(const float* __restrict__ rho,
              const short* __restrict__ Wp,
              const float* __restrict__ bias,
              const int*  __restrict__ counts,
              const int*  __restrict__ lists,
              float* __restrict__ out)
{
    const int s   = blockIdx.x & 3;
    const int mb  = blockIdx.x >> 2;
    const int cnt = counts[s];
    const int row0 = mb * BM;
    if (row0 >= cnt) return;
    int rows_here = cnt - row0; if (rows_here > BM) rows_here = BM;

    __shared__ int aidx[BM];
    __shared__ __align__(16) short Abuf[64 * 64 * 8];

    const int tid  = threadIdx.x;
    const int lane = tid & 63;
    const int w    = tid >> 6;
    const int lrow = lane & 15;
    const int lgr  = lane >> 4;

    if (tid < BM)
        aidx[tid] = lists[s * NTA + row0 + ((tid < rows_here) ? tid : 0)];
    __syncthreads();

    {
        const int srow  = tid >> 3;
        const int scol8 = tid & 7;
        const float* gsrc = rho + (size_t)aidx[srow] * DIM_O + scol8 * 4;
        const int c0   = scol8 >> 1;
        const int roww = srow ^ ((c0 & 3) << 1);
        const int dof  = (scol8 & 1) * 4;

        f32x4 v[16];
        #pragma unroll
        for (int r = 0; r < 16; ++r)
            v[r] = *(const f32x4*)(gsrc + r * 32);
        #pragma unroll
        for (int r = 0; r < 16; ++r) {
            bf16x4 a;
            #pragma unroll
            for (int q = 0; q < 4; ++q) a[q] = f2bf(v[r][q]);
            *(bf16x4*)&Abuf[((r * 4 + c0) * 64 + roww) * 8 + dof] = a;
        }
    }
    __syncthreads();

    const short* wbase = Wp + ((size_t)s * 512 + w * 4) * 512 + lane * 8;

    f32x4 acc[4][4];
    #pragma unroll
    for (int m = 0; m < 4; ++m)
        #pragma unroll
        for (int n = 0; n < 4; ++n) acc[m][n] = (f32x4)0.0f;

    #pragma unroll
    for (int kt = 0; kt < 8; ++kt) {
        bf16x8 bfr[2][4];
        #pragma unroll
        for (int ks = 0; ks < 2; ++ks)
            #pragma unroll
            for (int nf = 0; nf < 4; ++nf)
                bfr[ks][nf] = *(const bf16x8*)
                    (wbase + (size_t)((kt * 2 + ks) * 32 + nf) * 512);
        #pragma unroll
        for (int ks = 0; ks < 2; ++ks) {
            #pragma unroll
            for (int mf = 0; mf < 4; ++mf) {
                const int c = kt * 8 + ks * 4 + lgr;
                const int r = (mf * 16 + lrow) ^ ((lgr & 3) << 1);
                const bf16x8 afrag = *(const bf16x8*)&Abuf[(c * 64 + r) * 8];
                #pragma unroll
                for (int nf = 0; nf < 4; ++nf)
                    acc[mf][nf] = __builtin_amdgcn_mfma_f32_16x16x32_bf16(
                        afrag, bfr[ks][nf], acc[mf][nf], 0, 0, 0);
            }
        }
    }

    float bv[4];
    #pragma unroll
    for (int nf = 0; nf < 4; ++nf)
        bv[nf] = bias[s * NMAXD + w * 64 + nf * 16 + lrow];

    if constexpr (STORE) {
        #pragma unroll
        for (int mf = 0; mf < 4; ++mf) {
            #pragma unroll
            for (int q = 0; q < 4; ++q) {
                const int r = mf * 16 + lgr * 4 + q;
                if (r < rows_here) {
                    float* orow = out + (size_t)aidx[r] * NMAXD + w * 64 + lrow;
                    #pragma unroll
                    for (int nf = 0; nf < 4; ++nf)
                        orow[nf * 16] = acc[mf][nf][q] + bv[nf];
                }
            }
        }
    } else {
        float t = 0.f;
        #pragma unroll
        for (int mf = 0; mf < 4; ++mf)
            #pragma unroll
            for (int nf = 0; nf < 4; ++nf)
                t += acc[mf][nf][0] + acc[mf][nf][1] + acc[mf][nf][2]
                   + acc[mf][nf][3] + bv[nf];
        asm volatile("" :: "v"(t));
    }
}

extern "C" void kernel_launch(void* const* d_in, const int* in_sizes, int n_in,
                              void* d_out, int out_size, void* d_ws, size_t ws_size,
                              hipStream_t stream) {
    const float* rho = (const float*)d_in[0];
    const float* W   = (const float*)d_in[1];
    const float* b   = (const float*)d_in[2];
    const int*   sym = (const int*)d_in[3];
    float* out = (float*)d_out;

    int*   counts = (int*)d_ws;
    int*   lists  = (int*)((char*)d_ws + 1024);
    short* Wp     = (short*)((char*)d_ws + 1024 + (size_t)NSPE * NTA * 4);

    pack_w_kernel<<<(NSPE * DIM_O * NMAXD) / 256, 256, 0, stream>>>(W, Wp, counts);
    build_lists_kernel<<<NTA / 256, 256, 0, stream>>>(sym, counts, lists);

    // probes (write garbage into out; real gemm below overwrites everything)
    stream_tpl<1><<<NTA / 16, 256, 0, stream>>>(rho, out, counts, lists);
    stream_tpl<0><<<NTA / 16, 256, 0, stream>>>(rho, out, counts, lists);
    gemm_tpl<0><<<NSPE * (NTA / BM), 512, 0, stream>>>(rho, Wp, b, counts, lists, out);

    // real kernel, correct output
    gemm_tpl<1><<<NSPE * (NTA / BM), 512, 0, stream>>>(rho, Wp, b, counts, lists, out);
}